// Round 1
// baseline (1574.703 us; speedup 1.0000x reference)
//
#include <hip/hip_runtime.h>

#define D 128

__global__ __launch_bounds__(256) void deg_count_kernel(const int* __restrict__ dst,
                                                        float* __restrict__ deg, int E) {
  int e = blockIdx.x * 256 + threadIdx.x;
  if (e < E) atomicAdd(&deg[dst[e]], 1.0f);
}

__global__ __launch_bounds__(256) void dinv_kernel(float* deg_to_dinv, int N) {
  int i = blockIdx.x * 256 + threadIdx.x;
  if (i < N) deg_to_dinv[i] = rsqrtf(1.0f + deg_to_dinv[i]);
}

// H[N,128] = X[N,128] @ W[128,128], f32. 32 rows per block, X tile staged in LDS,
// W streamed through L1 (64KB, reused by every block).
__global__ __launch_bounds__(256) void gemm_kernel(const float* __restrict__ X,
                                                   const float* __restrict__ W,
                                                   float* __restrict__ H, int N) {
  __shared__ float xs[32 * D];
  int row0 = blockIdx.x * 32;
  // cooperative load of 32 rows (guarded), float4-coalesced
  #pragma unroll
  for (int j = 0; j < 4; ++j) {
    int f4 = threadIdx.x + j * 256;          // float4 index within 4096-float tile
    int row = row0 + (f4 >> 5);
    float4 v = make_float4(0.f, 0.f, 0.f, 0.f);
    if (row < N) v = *reinterpret_cast<const float4*>(X + (size_t)row0 * D + (size_t)f4 * 4);
    *reinterpret_cast<float4*>(xs + f4 * 4) = v;
  }
  __syncthreads();

  int tx = threadIdx.x & 127;   // output column
  int ty = threadIdx.x >> 7;    // row half (0/1)
  float acc[16];
  #pragma unroll
  for (int r = 0; r < 16; ++r) acc[r] = 0.f;

  for (int k = 0; k < D; k += 4) {
    float w0 = W[(k + 0) * D + tx];
    float w1 = W[(k + 1) * D + tx];
    float w2 = W[(k + 2) * D + tx];
    float w3 = W[(k + 3) * D + tx];
    #pragma unroll
    for (int r = 0; r < 16; ++r) {
      float4 xv = *reinterpret_cast<const float4*>(xs + (ty * 16 + r) * D + k);
      acc[r] = fmaf(xv.x, w0, acc[r]);
      acc[r] = fmaf(xv.y, w1, acc[r]);
      acc[r] = fmaf(xv.z, w2, acc[r]);
      acc[r] = fmaf(xv.w, w3, acc[r]);
    }
  }
  #pragma unroll
  for (int r = 0; r < 16; ++r) {
    int row = row0 + ty * 16 + r;
    if (row < N) H[(size_t)row * D + tx] = acc[r];
  }
}

// One edge per 128 threads: agg[dst] += H[src] * dinv[src]*dinv[dst]
__global__ __launch_bounds__(256) void scatter_kernel(const float* __restrict__ H,
                                                      const float* __restrict__ dinv,
                                                      const int* __restrict__ src,
                                                      const int* __restrict__ dst,
                                                      float* __restrict__ agg, int E) {
  long long idx = (long long)blockIdx.x * 256 + threadIdx.x;
  int e = (int)(idx >> 7);
  int c = (int)(idx & 127);
  if (e >= E) return;
  int s = src[e];
  int d = dst[e];
  float norm = dinv[s] * dinv[d];
  atomicAdd(agg + (size_t)d * D + c, H[(size_t)s * D + c] * norm);
}

// agg = (maybe relu)(agg + H * dinv^2 + bias)
__global__ __launch_bounds__(256) void epilogue_kernel(float* __restrict__ agg,
                                                       const float* __restrict__ H,
                                                       const float* __restrict__ dinv,
                                                       const float* __restrict__ bias,
                                                       int N, int do_relu) {
  int idx = blockIdx.x * 256 + threadIdx.x;
  if (idx >= N * D) return;
  int i = idx >> 7;
  int c = idx & 127;
  float di = dinv[i];
  float v = agg[idx] + H[idx] * di * di + bias[c];
  if (do_relu) v = fmaxf(v, 0.f);
  agg[idx] = v;
}

extern "C" void kernel_launch(void* const* d_in, const int* in_sizes, int n_in,
                              void* d_out, int out_size, void* d_ws, size_t ws_size,
                              hipStream_t stream) {
  const float* x  = (const float*)d_in[0];
  const int* edge = (const int*)d_in[1];
  const float* W1 = (const float*)d_in[2];
  const float* b1 = (const float*)d_in[3];
  const float* W2 = (const float*)d_in[4];
  const float* b2 = (const float*)d_in[5];
  const int N = in_sizes[0] / D;   // 50000
  const int E = in_sizes[1] / 2;   // 1.6M
  const int* srcp = edge;
  const int* dstp = edge + E;
  float* out = (float*)d_out;

  char* ws = (char*)d_ws;
  float* dinv = (float*)ws;                                   // N floats
  size_t off = (((size_t)N * 4) + 255) & ~(size_t)255;
  size_t hbytes = (size_t)N * D * sizeof(float);              // 25.6 MB
  float* bufH = (float*)(ws + off);
  float* bufA = (float*)(ws + off + ((hbytes + 255) & ~(size_t)255));

  // degrees -> dinv
  hipMemsetAsync(dinv, 0, (size_t)N * 4, stream);
  deg_count_kernel<<<(E + 255) / 256, 256, 0, stream>>>(dstp, dinv, E);
  dinv_kernel<<<(N + 255) / 256, 256, 0, stream>>>(dinv, N);

  long long sc_threads = (long long)E * D;
  int sc_blocks = (int)((sc_threads + 255) / 256);
  int ep_blocks = (N * D + 255) / 256;
  int gemm_blocks = (N + 31) / 32;

  // ---- layer 1: h1 = relu(A @ (x@W1) + b1) ----
  gemm_kernel<<<gemm_blocks, 256, 0, stream>>>(x, W1, bufH, N);
  hipMemsetAsync(bufA, 0, hbytes, stream);
  scatter_kernel<<<sc_blocks, 256, 0, stream>>>(bufH, dinv, srcp, dstp, bufA, E);
  epilogue_kernel<<<ep_blocks, 256, 0, stream>>>(bufA, bufH, dinv, b1, N, 1);

  // ---- layer 2: z = A @ (h1@W2) + b2 ----
  gemm_kernel<<<gemm_blocks, 256, 0, stream>>>(bufA, W2, bufH, N);
  hipMemsetAsync(out, 0, hbytes, stream);
  scatter_kernel<<<sc_blocks, 256, 0, stream>>>(bufH, dinv, srcp, dstp, out, E);
  epilogue_kernel<<<ep_blocks, 256, 0, stream>>>(out, bufH, dinv, b2, N, 0);
}

// Round 2
// 579.763 us; speedup vs baseline: 2.7161x; 2.7161x over previous
//
#include <hip/hip_runtime.h>

#define D 128

// ---- CSR build ----------------------------------------------------------

__global__ __launch_bounds__(256) void deg_kernel(const int* __restrict__ dst,
                                                  int* __restrict__ deg, int E) {
  int e = blockIdx.x * 256 + threadIdx.x;
  if (e < E) atomicAdd(&deg[dst[e]], 1);
}

__global__ __launch_bounds__(256) void dinv_kernel(const int* __restrict__ deg,
                                                   float* __restrict__ dinv, int N) {
  int i = blockIdx.x * 256 + threadIdx.x;
  if (i < N) dinv[i] = rsqrtf(1.0f + (float)deg[i]);
}

// Single-block exclusive scan of deg[0..N) -> offsets[0..N], cursor copy.
__global__ __launch_bounds__(1024) void scan_kernel(const int* __restrict__ deg,
                                                    int* __restrict__ offsets,
                                                    int* __restrict__ cursor, int N) {
  __shared__ int tsum[1024];
  int t = threadIdx.x;
  int chunk = (N + 1023) / 1024;
  int beg = t * chunk;
  int end = min(beg + chunk, N);
  int s = 0;
  for (int i = beg; i < end; ++i) s += deg[i];
  tsum[t] = s;
  __syncthreads();
  // Hillis-Steele inclusive scan across 1024 threads
  for (int off = 1; off < 1024; off <<= 1) {
    int v = (t >= off) ? tsum[t - off] : 0;
    __syncthreads();
    tsum[t] += v;
    __syncthreads();
  }
  int run = (t == 0) ? 0 : tsum[t - 1];  // exclusive prefix for this chunk
  for (int i = beg; i < end; ++i) {
    offsets[i] = run;
    cursor[i] = run;
    run += deg[i];
  }
  if (t == 1023) offsets[N] = run;  // = E
}

// Counting-sort edges into CSR buckets; pack {src, norm} into 8B.
__global__ __launch_bounds__(256) void place_kernel(const int* __restrict__ src,
                                                    const int* __restrict__ dst,
                                                    const float* __restrict__ dinv,
                                                    int* __restrict__ cursor,
                                                    int2* __restrict__ csr, int E) {
  int e = blockIdx.x * 256 + threadIdx.x;
  if (e >= E) return;
  int s = src[e];
  int d = dst[e];
  int pos = atomicAdd(&cursor[d], 1);
  int2 p;
  p.x = s;
  p.y = __float_as_int(dinv[s] * dinv[d]);
  csr[pos] = p;
}

// ---- GEMM: H[N,128] = X[N,128] @ W[128,128] ------------------------------

__global__ __launch_bounds__(256) void gemm_kernel(const float* __restrict__ X,
                                                   const float* __restrict__ W,
                                                   float* __restrict__ H, int N) {
  __shared__ float xs[32 * D];
  int row0 = blockIdx.x * 32;
  #pragma unroll
  for (int j = 0; j < 4; ++j) {
    int f4 = threadIdx.x + j * 256;
    int row = row0 + (f4 >> 5);
    float4 v = make_float4(0.f, 0.f, 0.f, 0.f);
    if (row < N) v = *reinterpret_cast<const float4*>(X + (size_t)row0 * D + (size_t)f4 * 4);
    *reinterpret_cast<float4*>(xs + f4 * 4) = v;
  }
  __syncthreads();

  int tx = threadIdx.x & 127;
  int ty = threadIdx.x >> 7;
  float acc[16];
  #pragma unroll
  for (int r = 0; r < 16; ++r) acc[r] = 0.f;

  for (int k = 0; k < D; k += 4) {
    float w0 = W[(k + 0) * D + tx];
    float w1 = W[(k + 1) * D + tx];
    float w2 = W[(k + 2) * D + tx];
    float w3 = W[(k + 3) * D + tx];
    #pragma unroll
    for (int r = 0; r < 16; ++r) {
      float4 xv = *reinterpret_cast<const float4*>(xs + (ty * 16 + r) * D + k);
      acc[r] = fmaf(xv.x, w0, acc[r]);
      acc[r] = fmaf(xv.y, w1, acc[r]);
      acc[r] = fmaf(xv.z, w2, acc[r]);
      acc[r] = fmaf(xv.w, w3, acc[r]);
    }
  }
  #pragma unroll
  for (int r = 0; r < 16; ++r) {
    int row = row0 + ty * 16 + r;
    if (row < N) H[(size_t)row * D + tx] = acc[r];
  }
}

// ---- Aggregation: one wave per dst node, fused epilogue ------------------
// out[n] = (relu?)( sum_{e:dst=e} H[src_e]*norm_e + H[n]*dinv[n]^2 + bias )

__global__ __launch_bounds__(256) void agg_kernel(const float* __restrict__ H,
                                                  const int* __restrict__ offsets,
                                                  const int2* __restrict__ csr,
                                                  const float* __restrict__ dinv,
                                                  const float* __restrict__ bias,
                                                  float* __restrict__ out,
                                                  int N, int do_relu) {
  int n = blockIdx.x * 4 + (threadIdx.x >> 6);
  int lane = threadIdx.x & 63;
  if (n >= N) return;
  int beg = offsets[n];
  int end = offsets[n + 1];

  float2 acc = make_float2(0.f, 0.f);
  int j = beg;
  for (; j + 2 <= end; j += 2) {
    int2 p0 = csr[j];
    int2 p1 = csr[j + 1];
    float m0 = __int_as_float(p0.y);
    float m1 = __int_as_float(p1.y);
    float2 h0 = *reinterpret_cast<const float2*>(H + (size_t)p0.x * D + lane * 2);
    float2 h1 = *reinterpret_cast<const float2*>(H + (size_t)p1.x * D + lane * 2);
    acc.x = fmaf(h0.x, m0, acc.x);
    acc.y = fmaf(h0.y, m0, acc.y);
    acc.x = fmaf(h1.x, m1, acc.x);
    acc.y = fmaf(h1.y, m1, acc.y);
  }
  if (j < end) {
    int2 p0 = csr[j];
    float m0 = __int_as_float(p0.y);
    float2 h0 = *reinterpret_cast<const float2*>(H + (size_t)p0.x * D + lane * 2);
    acc.x = fmaf(h0.x, m0, acc.x);
    acc.y = fmaf(h0.y, m0, acc.y);
  }

  float di = dinv[n];
  float dii = di * di;
  float2 hs = *reinterpret_cast<const float2*>(H + (size_t)n * D + lane * 2);
  acc.x = fmaf(hs.x, dii, acc.x);
  acc.y = fmaf(hs.y, dii, acc.y);
  acc.x += bias[lane * 2];
  acc.y += bias[lane * 2 + 1];
  if (do_relu) {
    acc.x = fmaxf(acc.x, 0.f);
    acc.y = fmaxf(acc.y, 0.f);
  }
  *reinterpret_cast<float2*>(out + (size_t)n * D + lane * 2) = acc;
}

// ---- launch ---------------------------------------------------------------

extern "C" void kernel_launch(void* const* d_in, const int* in_sizes, int n_in,
                              void* d_out, int out_size, void* d_ws, size_t ws_size,
                              hipStream_t stream) {
  const float* x  = (const float*)d_in[0];
  const int* edge = (const int*)d_in[1];
  const float* W1 = (const float*)d_in[2];
  const float* b1 = (const float*)d_in[3];
  const float* W2 = (const float*)d_in[4];
  const float* b2 = (const float*)d_in[5];
  const int N = in_sizes[0] / D;   // 50000
  const int E = in_sizes[1] / 2;   // 1.6M
  const int* srcp = edge;
  const int* dstp = edge + E;
  float* out = (float*)d_out;

  auto align = [](size_t v) { return (v + 255) & ~(size_t)255; };
  char* ws = (char*)d_ws;
  size_t o = 0;
  int*   deg     = (int*)(ws + o);  o += align((size_t)N * 4);
  float* dinv    = (float*)(ws + o); o += align((size_t)N * 4);
  int*   offsets = (int*)(ws + o);  o += align((size_t)(N + 1) * 4);
  int*   cursor  = (int*)(ws + o);  o += align((size_t)N * 4);
  int2*  csr     = (int2*)(ws + o); o += align((size_t)E * 8);
  float* bufH    = (float*)(ws + o); o += align((size_t)N * D * 4);

  // CSR build (shared by both layers)
  hipMemsetAsync(deg, 0, (size_t)N * 4, stream);
  deg_kernel<<<(E + 255) / 256, 256, 0, stream>>>(dstp, deg, E);
  dinv_kernel<<<(N + 255) / 256, 256, 0, stream>>>(deg, dinv, N);
  scan_kernel<<<1, 1024, 0, stream>>>(deg, offsets, cursor, N);
  place_kernel<<<(E + 255) / 256, 256, 0, stream>>>(srcp, dstp, dinv, cursor, csr, E);

  int gemm_blocks = (N + 31) / 32;
  int agg_blocks = (N + 3) / 4;

  // layer 1: h1 = relu(A @ (x@W1) + b1)  -> stored in d_out (scratch reuse)
  gemm_kernel<<<gemm_blocks, 256, 0, stream>>>(x, W1, bufH, N);
  agg_kernel<<<agg_blocks, 256, 0, stream>>>(bufH, offsets, csr, dinv, b1, out, N, 1);

  // layer 2: z = A @ (h1@W2) + b2  -> final result in d_out
  gemm_kernel<<<gemm_blocks, 256, 0, stream>>>(out, W2, bufH, N);
  agg_kernel<<<agg_blocks, 256, 0, stream>>>(bufH, offsets, csr, dinv, b2, out, N, 0);
}